// Round 8
// baseline (188.787 us; speedup 1.0000x reference)
//
#include <hip/hip_runtime.h>

// mp: [1, 21, 16, 256, 256] fp32
#define CC   21
#define DD   16
#define HH   256
#define WW   256
#define HWP  (HH * WW)      // 65536
#define DHW  (DD * HWP)     // 1048576

typedef float f4a __attribute__((ext_vector_type(4), aligned(16)));
__device__ __forceinline__ f4a f4add(f4a a, f4a b) { return a + b; }

// global -> LDS direct (async DMA, no VGPR round-trip). Per-lane GLOBAL addr,
// wave-uniform LDS base + lane*16B. Size must be a literal 16.
#define GLDS16(gp, lp)                                                        \
    __builtin_amdgcn_global_load_lds(                                         \
        (const __attribute__((address_space(1))) void*)(gp),                  \
        (__attribute__((address_space(3))) void*)(lp), 16, 0, 0)

// ---------------------------------------------------------------------------
// K1: TH=16 scale-up of the verified R7 structure (raw-stage via
// global_load_lds + in-place D-chain + H-pass). H-halo redundancy drops
// 12/8=1.5x -> 20/16=1.25x (reads 132 -> 110 MB) and block pulses halve.
// LDS raw[d][py][32f] packed: word = d*640 + py*32 + x4*4, 10240 words =
// 40 KB -> exactly 4 blocks/CU. Stage = 40 x global_load_lds_dwordx4
// (10 per wave, all waves), linear LDS (word = idx4*4), no register RT.
// Phase A (tid<160): column (py,x4) reads its 16 planes from LDS, runs BOTH
// verified sliding chains, writes back in place (same modular bank pattern
// as R7: plane stride 640 === 0 mod 32, measured 0 conflicts there).
// Phase B: verified H-pass, 8 iters (y 0..15, dout 0..15).
// All sums / clamps / store addresses bit-identical to the verified kernel:
// output row h reads clamped rows h-2..h+2 exactly as before.
// ---------------------------------------------------------------------------
#define PYS  20                       // staged rows per plane
#define A_WORDS (DD * PYS * 32)       // 10240 floats = 40960 B

#define NB1  (8 * 16 * CC)            // wt x hb x ch = 2688 blocks
#define CHK1 (NB1 / 8)                // 336 per XCD (bijective)

__global__ __launch_bounds__(256, 4) void dh_blur_kernel(const float* __restrict__ mp,
                                                         float* __restrict__ out) {
    __shared__ float A[A_WORDS];
    const int tid = threadIdx.x;

    // bijective XCD-chunked order
    const int bid = blockIdx.x;
    const int t   = (bid & 7) * CHK1 + (bid >> 3);
    const int hb  = t & 15;
    const int wt  = (t >> 4) & 7;
    const int ch  = t >> 7;
    const int w0  = wt * 32;
    const int h0  = hb * 16;
    const float* __restrict__ src = mp + (size_t)ch * DHW + w0;

    // ---- stage: 40 x global_load_lds_dwordx4, 10 per wave ----
    {
        const int wv   = tid >> 6;         // wave 0..3
        const int lane = tid & 63;
#pragma unroll
        for (int j = 0; j < 10; ++j) {
            const int inst = wv * 10 + j;              // 0..39
            const int idx4 = inst * 64 + lane;         // vec4 index 0..2559
            const int d    = idx4 / 160;               // plane 0..15 (160 vec4/plane)
            const int r    = idx4 - d * 160;
            const int py   = r >> 3;                   // 0..19
            const int x4   = r & 7;                    // 0..7
            const int h    = min(HH - 1, max(0, h0 + py - 2));
            const float* gp = src + (size_t)d * HWP + (size_t)h * WW + x4 * 4;
            GLDS16(gp, &A[inst * 256]);                // linear: word = idx4*4
        }
    }
    __syncthreads();   // raw tile resident in LDS

    // ---- phase A: in-place D-blur per column (verified chains) ----
    if (tid < 160) {
        const int py = tid >> 3;             // 0..19
        const int x4 = tid & 7;              // quad 0..7
        float* colA = &A[py * 32 + x4 * 4];  // + d*640

        f4a P[16];
#pragma unroll
        for (int d = 0; d < 16; ++d) P[d] = *(const f4a*)(colA + d * 640);

        constexpr int M0[12] = {0, 0, 0, 1, 2, 3, 4, 5, 6, 7, 8, 9};
        constexpr int M1[12] = {6, 7, 8, 9, 10, 11, 12, 13, 14, 15, 15, 15};

        {   // s = 0: planes 0..7
            f4a sum = f4add(f4add(f4add(P[M0[0]], P[M0[1]]),
                                  f4add(P[M0[2]], P[M0[3]])), P[M0[4]]);
#pragma unroll
            for (int i = 0; i < 8; ++i) {
                *(f4a*)(colA + i * 640) = sum;
                if (i < 7) sum = sum - P[M0[i]] + P[M0[i + 5]];
            }
        }
        {   // s = 1: planes 8..15
            f4a sum = f4add(f4add(f4add(P[M1[0]], P[M1[1]]),
                                  f4add(P[M1[2]], P[M1[3]])), P[M1[4]]);
#pragma unroll
            for (int i = 0; i < 8; ++i) {
                *(f4a*)(colA + (8 + i) * 640) = sum;
                if (i < 7) sum = sum - P[M1[i]] + P[M1[i + 5]];
            }
        }
    }
    __syncthreads();

    // ---- phase B: verified H-pass + stores (8 iters) ----
#pragma unroll
    for (int it = 0; it < 8; ++it) {
        const int tt   = tid + it * 256;       // 0..2047
        const int xx4  = tt & 7;
        const int y    = (tt >> 3) & 15;       // 0..15
        const int dout = tt >> 7;              // 0..15

        const float* b = &A[dout * 640 + y * 32 + xx4 * 4];
        f4a a = *(const f4a*)b;
#pragma unroll
        for (int k = 1; k < 5; ++k) a = f4add(a, *(const f4a*)(b + k * 32));

        *(f4a*)(out + (size_t)ch * DHW + (size_t)dout * HWP
                + (size_t)(h0 + y) * WW + w0 + xx4 * 4) = a;
    }
}

// ---------------------------------------------------------------------------
// K2: W-blur + weighted-median, verbatim verified round-1 kernel (6.5 TB/s).
// ---------------------------------------------------------------------------
#define ROWP 264   // 2 pad + 2 lo-edge + 256 data + 2 hi-edge + 2 pad

__global__ __launch_bounds__(256) void wmedian_kernel(float* __restrict__ y4) {
    __shared__ float R[CC * ROWP];

    const int h = blockIdx.x;
    const int d = blockIdx.y;
    const int tid = threadIdx.x;
    float* __restrict__ base = y4 + (size_t)d * HWP + (size_t)h * WW;

    for (int idx = tid; idx < CC * 64; idx += 256) {
        const int c  = idx >> 6;
        const int w4 = idx & 63;
        *(f4a*)(&R[c * ROWP + 4 + w4 * 4]) = *(const f4a*)(base + (size_t)c * DHW + w4 * 4);
    }
    if (tid < CC) {
        const float v0 = base[(size_t)tid * DHW];
        const float vL = base[(size_t)tid * DHW + (WW - 1)];
        R[tid * ROWP + 2]   = v0;
        R[tid * ROWP + 3]   = v0;
        R[tid * ROWP + 260] = vL;
        R[tid * ROWP + 261] = vL;
    }
    __syncthreads();

    const int w = tid;   // 0..255
    float v[CC];
    float tot = 0.f;
#pragma unroll
    for (int c = 0; c < CC; ++c) {
        const float* r = &R[c * ROWP + 2 + w];           // r[0] = value at w-2
        v[c] = ((((r[0] + r[1]) + r[2]) + r[3]) + r[4]); // verified W order
        tot += v[c];
    }
    const float inv = 1.0f / tot;

    float s = 0.f, sv0 = 0.f, sv1 = 0.f;
    int m0 = 0, m1 = 0;
#pragma unroll
    for (int c = 0; c < CC; ++c) {
        const float yn = v[c] * inv;
        const float sn = s + yn;
        if (c == 0) { sv0 = yn; sv1 = yn; }                           // defaults
        if (v[c] > 0.f && sn < 0.5f) { m0 = c; sv0 = yn; }            // last qualifying
        if (m1 == 0 && c > 0 && sn > 0.5f) { m1 = c; sv1 = yn; }      // first qualifying
        s = sn;
    }

#pragma unroll
    for (int c = 0; c < CC; ++c) {
        base[(size_t)c * DHW + w] = (c == m0) ? sv0 : ((c == m1) ? sv1 : 0.f);
    }
}

extern "C" void kernel_launch(void* const* d_in, const int* in_sizes, int n_in,
                              void* d_out, int out_size, void* d_ws, size_t ws_size,
                              hipStream_t stream) {
    const float* mp = (const float*)d_in[0];
    float* out = (float*)d_out;

    dh_blur_kernel<<<NB1, 256, 0, stream>>>(mp, out);       // 2688 blocks, XCD-chunked
    wmedian_kernel<<<dim3(HH, DD), 256, 0, stream>>>(out);  // 4096 blocks
}

// Round 9
// 185.216 us; speedup vs baseline: 1.0193x; 1.0193x over previous
//
#include <hip/hip_runtime.h>

// mp: [1, 21, 16, 256, 256] fp32
#define CC   21
#define DD   16
#define HH   256
#define WW   256
#define HWP  (HH * WW)      // 65536
#define DHW  (DD * HWP)     // 1048576

typedef float f4a __attribute__((ext_vector_type(4), aligned(16)));
__device__ __forceinline__ f4a f4add(f4a a, f4a b) { return a + b; }

// global -> LDS direct (async DMA, no VGPR round-trip). Per-lane GLOBAL addr,
// wave-uniform LDS base + lane*16B. Size must be a literal 16.
#define GLDS16(gp, lp)                                                        \
    __builtin_amdgcn_global_load_lds(                                         \
        (const __attribute__((address_space(1))) void*)(gp),                  \
        (__attribute__((address_space(3))) void*)(lp), 16, 0, 0)

// ---------------------------------------------------------------------------
// K1: TW=64 variant of the verified R7 structure — the granularity-vs-
// occupancy discriminator. All global segments double to 256 B (reads AND
// stores); LDS 48 KB -> 3 blocks/CU. Same 2-barrier phase structure:
//   stage: 48 x global_load_lds_dwordx4 (12/wave, all waves, linear LDS)
//   phase A (tid<192): column (py,x4) reads its 16 planes from LDS, runs
//     BOTH verified sliding D-chains, writes back in place.
//   phase B: verified H-pass (row stride 64), 256-B global stores.
// LDS word = d*768 + py*64 + x4*4; plane stride 768 === 0 mod 32, x4*4
// covers each bank quad exactly twice per wave -> same structural-minimum
// bank pattern as R7 (measured 0 conflicts there).
// Output element (d,h,w) reads the same clamped rows with the same chains
// as the verified kernel -> bitwise-identical results.
// ---------------------------------------------------------------------------
#define PYS  12                       // staged rows per plane
#define TWK  64                       // tile width
#define A_WORDS (DD * PYS * TWK)      // 12288 floats = 49152 B -> 3 blocks/CU

#define NB1  (4 * 32 * CC)            // wt x yb x ch = 2688 blocks
#define CHK1 (NB1 / 8)                // 336 per XCD (bijective)

__global__ __launch_bounds__(256, 3) void dh_blur_kernel(const float* __restrict__ mp,
                                                         float* __restrict__ out) {
    __shared__ float A[A_WORDS];
    const int tid = threadIdx.x;

    // bijective XCD-chunked order
    const int bid = blockIdx.x;
    const int t   = (bid & 7) * CHK1 + (bid >> 3);
    const int yb  = t & 31;
    const int wt  = (t >> 5) & 3;
    const int ch  = t >> 7;
    const int w0  = wt * TWK;
    const int h0  = yb * 8;
    const float* __restrict__ src = mp + (size_t)ch * DHW + w0;

    // ---- stage: 48 x global_load_lds_dwordx4, 12 per wave ----
    {
        const int wv   = tid >> 6;         // wave 0..3
        const int lane = tid & 63;
#pragma unroll
        for (int j = 0; j < 12; ++j) {
            const int inst = wv * 12 + j;              // 0..47
            const int idx4 = inst * 64 + lane;         // vec4 index 0..3071
            const int d    = idx4 / 192;               // plane 0..15 (192 vec4/plane)
            const int r    = idx4 - d * 192;
            const int py   = r >> 4;                   // 0..11
            const int x4   = r & 15;                   // 0..15
            const int h    = min(HH - 1, max(0, h0 + py - 2));
            const float* gp = src + (size_t)d * HWP + (size_t)h * WW + x4 * 4;
            GLDS16(gp, &A[inst * 256]);                // linear: word = idx4*4
        }
    }
    __syncthreads();   // raw tile resident in LDS

    // ---- phase A: in-place D-blur per column (verified chains) ----
    if (tid < 192) {
        const int py = tid >> 4;              // 0..11
        const int x4 = tid & 15;              // quad 0..15
        float* colA = &A[py * TWK + x4 * 4];  // + d*768

        f4a P[16];
#pragma unroll
        for (int d = 0; d < 16; ++d) P[d] = *(const f4a*)(colA + d * 768);

        constexpr int M0[12] = {0, 0, 0, 1, 2, 3, 4, 5, 6, 7, 8, 9};
        constexpr int M1[12] = {6, 7, 8, 9, 10, 11, 12, 13, 14, 15, 15, 15};

        {   // s = 0: planes 0..7
            f4a sum = f4add(f4add(f4add(P[M0[0]], P[M0[1]]),
                                  f4add(P[M0[2]], P[M0[3]])), P[M0[4]]);
#pragma unroll
            for (int i = 0; i < 8; ++i) {
                *(f4a*)(colA + i * 768) = sum;
                if (i < 7) sum = sum - P[M0[i]] + P[M0[i + 5]];
            }
        }
        {   // s = 1: planes 8..15
            f4a sum = f4add(f4add(f4add(P[M1[0]], P[M1[1]]),
                                  f4add(P[M1[2]], P[M1[3]])), P[M1[4]]);
#pragma unroll
            for (int i = 0; i < 8; ++i) {
                *(f4a*)(colA + (8 + i) * 768) = sum;
                if (i < 7) sum = sum - P[M1[i]] + P[M1[i + 5]];
            }
        }
    }
    __syncthreads();

    // ---- phase B: verified H-pass + 256-B stores (8 iters) ----
#pragma unroll
    for (int it = 0; it < 8; ++it) {
        const int tt   = tid + it * 256;       // 0..2047
        const int xx4  = tt & 15;              // 0..15
        const int y    = (tt >> 4) & 7;        // 0..7
        const int dout = tt >> 7;              // 0..15

        const float* b = &A[dout * 768 + y * TWK + xx4 * 4];
        f4a a = *(const f4a*)b;
#pragma unroll
        for (int k = 1; k < 5; ++k) a = f4add(a, *(const f4a*)(b + k * TWK));

        *(f4a*)(out + (size_t)ch * DHW + (size_t)dout * HWP
                + (size_t)(h0 + y) * WW + w0 + xx4 * 4) = a;
    }
}

// ---------------------------------------------------------------------------
// K2: W-blur + weighted-median, verbatim verified round-1 kernel (6.5 TB/s).
// ---------------------------------------------------------------------------
#define ROWP 264   // 2 pad + 2 lo-edge + 256 data + 2 hi-edge + 2 pad

__global__ __launch_bounds__(256) void wmedian_kernel(float* __restrict__ y4) {
    __shared__ float R[CC * ROWP];

    const int h = blockIdx.x;
    const int d = blockIdx.y;
    const int tid = threadIdx.x;
    float* __restrict__ base = y4 + (size_t)d * HWP + (size_t)h * WW;

    for (int idx = tid; idx < CC * 64; idx += 256) {
        const int c  = idx >> 6;
        const int w4 = idx & 63;
        *(f4a*)(&R[c * ROWP + 4 + w4 * 4]) = *(const f4a*)(base + (size_t)c * DHW + w4 * 4);
    }
    if (tid < CC) {
        const float v0 = base[(size_t)tid * DHW];
        const float vL = base[(size_t)tid * DHW + (WW - 1)];
        R[tid * ROWP + 2]   = v0;
        R[tid * ROWP + 3]   = v0;
        R[tid * ROWP + 260] = vL;
        R[tid * ROWP + 261] = vL;
    }
    __syncthreads();

    const int w = tid;   // 0..255
    float v[CC];
    float tot = 0.f;
#pragma unroll
    for (int c = 0; c < CC; ++c) {
        const float* r = &R[c * ROWP + 2 + w];           // r[0] = value at w-2
        v[c] = ((((r[0] + r[1]) + r[2]) + r[3]) + r[4]); // verified W order
        tot += v[c];
    }
    const float inv = 1.0f / tot;

    float s = 0.f, sv0 = 0.f, sv1 = 0.f;
    int m0 = 0, m1 = 0;
#pragma unroll
    for (int c = 0; c < CC; ++c) {
        const float yn = v[c] * inv;
        const float sn = s + yn;
        if (c == 0) { sv0 = yn; sv1 = yn; }                           // defaults
        if (v[c] > 0.f && sn < 0.5f) { m0 = c; sv0 = yn; }            // last qualifying
        if (m1 == 0 && c > 0 && sn > 0.5f) { m1 = c; sv1 = yn; }      // first qualifying
        s = sn;
    }

#pragma unroll
    for (int c = 0; c < CC; ++c) {
        base[(size_t)c * DHW + w] = (c == m0) ? sv0 : ((c == m1) ? sv1 : 0.f);
    }
}

extern "C" void kernel_launch(void* const* d_in, const int* in_sizes, int n_in,
                              void* d_out, int out_size, void* d_ws, size_t ws_size,
                              hipStream_t stream) {
    const float* mp = (const float*)d_in[0];
    float* out = (float*)d_out;

    dh_blur_kernel<<<NB1, 256, 0, stream>>>(mp, out);       // 2688 blocks, XCD-chunked
    wmedian_kernel<<<dim3(HH, DD), 256, 0, stream>>>(out);  // 4096 blocks
}